// Round 15
// baseline (39.050 us; speedup 1.0000x reference)
//
#include <hip/hip_runtime.h>

#define BB 4
#define CIN 3
#define HH 512
#define WW 512
#define KK 9
#define COUT 3
#define HO 510
#define WO 510
#define HW (HH * WW)
#define HOWO (HO * WO)

// padded f16 NHWC buffer: [B][PR][PC] x uint2 (c0c1, c2pad), origin (PADR, PADC)
#define PR 518
#define PC 520
#define PADR 3
#define PADC 4
#define XP_BYTES ((size_t)BB * PR * PC * sizeof(uint2))

typedef __fp16 h2 __attribute__((ext_vector_type(2)));

// 16-byte vector with only 8-byte alignment guarantee (corner-row loads)
struct __attribute__((aligned(8))) uint4a8 { uint4 v; };

__device__ __forceinline__ h2 pkrtz(float a, float b) {
    return __builtin_amdgcn_cvt_pkrtz(a, b);
}
__device__ __forceinline__ float fdot2f(h2 a, h2 b, float c) {
    return __builtin_amdgcn_fdot2(a, b, c, false);
}
__device__ __forceinline__ h2 uint_as_h2(unsigned u) {
    return __builtin_bit_cast(h2, u);
}
__device__ __forceinline__ unsigned h2_as_uint(h2 h) {
    return __builtin_bit_cast(unsigned, h);
}
// w1 element: channel ch, input channel c, kernel row r, col s
__device__ __forceinline__ float w1e(const float* w1, int ch, int c, int r, int s) {
    return w1[ch * 27 + c * 9 + r * 3 + s];
}

// ------------- kernel 1: NCHW f32 -> padded f16 NHWC, 2 px/thread -----------
__global__ __launch_bounds__(256) void repack_padh2(
    const float* __restrict__ x, uint2* __restrict__ xp)
{
    constexpr int PCH = PC / 2;  // 260 column-pairs
    const int idx = blockIdx.x * blockDim.x + threadIdx.x;
    const int total = BB * PR * PCH;
    if (idx >= total) return;
    const int b = idx / (PR * PCH);
    const int rem = idx - b * (PR * PCH);
    const int y = rem / PCH;
    const int q = rem - y * PCH;
    const int ys = y - PADR;
    const int xs = 2 * q - PADC;  // even; pair is all-or-nothing valid
    uint4 v = make_uint4(0u, 0u, 0u, 0u);
    if ((unsigned)ys < (unsigned)HH && (unsigned)xs < (unsigned)WW) {
        const float* xb = x + (size_t)b * CIN * HW;
        const int p = ys * WW + xs;
        const float2 a0 = *reinterpret_cast<const float2*>(xb + p);
        const float2 a1 = *reinterpret_cast<const float2*>(xb + HW + p);
        const float2 a2 = *reinterpret_cast<const float2*>(xb + 2 * HW + p);
        v.x = h2_as_uint(pkrtz(a0.x, a1.x));
        v.y = h2_as_uint(pkrtz(a2.x, 0.f));
        v.z = h2_as_uint(pkrtz(a0.y, a1.y));
        v.w = h2_as_uint(pkrtz(a2.y, 0.f));
    }
    reinterpret_cast<uint4*>(xp)[idx] = v;
}

// -------- kernel 2: fused, 1 px/thread; corner-ROW loads as dwordx4 --------
__global__ __launch_bounds__(256) void deform_fused10(
    const uint2* __restrict__ xp,   // [B][PR][PC] padded f16 NHWC
    const float* __restrict__ w1,   // [18][3][3][3]
    const float* __restrict__ b1,   // [18]
    const float* __restrict__ w2,   // [3][3][3][3]
    const float* __restrict__ b2,   // [3]
    float* __restrict__ out)        // [B][3][HO][WO]
{
    // conv1 weights: s_w1h[k*9+pos] = {wy_c01, wy_c2x, wx_c01, wx_c2x}
    __shared__ uint4 s_w1h[KK * 9];
    __shared__ float s_b[18];
    // conv2 weights packed h2: per tap k, wa = {o0_c01,o0_c2x,o1_c01,o1_c2x},
    // wb = {o2_c01, o2_c2x}
    __shared__ uint4 s_w2a[KK];
    __shared__ uint2 s_w2b[KK];
    __shared__ float s_b2[COUT];

    if (threadIdx.x < KK * 9) {
        const int k = threadIdx.x / 9;
        const int pos = threadIdx.x % 9;
        const int r = pos / 3, s = pos % 3;
        uint4 u;
        u.x = h2_as_uint(pkrtz(w1e(w1, 2 * k, 0, r, s), w1e(w1, 2 * k, 1, r, s)));
        u.y = h2_as_uint(pkrtz(w1e(w1, 2 * k, 2, r, s), 0.f));
        u.z = h2_as_uint(pkrtz(w1e(w1, 2 * k + 1, 0, r, s), w1e(w1, 2 * k + 1, 1, r, s)));
        u.w = h2_as_uint(pkrtz(w1e(w1, 2 * k + 1, 2, r, s), 0.f));
        s_w1h[threadIdx.x] = u;
    }
    if (threadIdx.x < KK) {
        const int k = threadIdx.x;
        uint4 wa;
        wa.x = h2_as_uint(pkrtz(w2[k], w2[9 + k]));
        wa.y = h2_as_uint(pkrtz(w2[18 + k], 0.f));
        wa.z = h2_as_uint(pkrtz(w2[27 + k], w2[36 + k]));
        wa.w = h2_as_uint(pkrtz(w2[45 + k], 0.f));
        s_w2a[k] = wa;
        uint2 wb;
        wb.x = h2_as_uint(pkrtz(w2[54 + k], w2[63 + k]));
        wb.y = h2_as_uint(pkrtz(w2[72 + k], 0.f));
        s_w2b[k] = wb;
    }
    if (threadIdx.x < 18) s_b[threadIdx.x] = b1[threadIdx.x];
    if (threadIdx.x < COUT) s_b2[threadIdx.x] = b2[threadIdx.x];
    __syncthreads();

    const int idx = blockIdx.x * 256 + threadIdx.x;
    if (idx >= BB * HOWO) return;
    const int j = idx % WO;
    const int t1 = idx / WO;
    const int i = t1 % HO;
    const int b = t1 / HO;

    const uint2* xb2 = xp + (size_t)b * (PR * PC);

    // ---- phase A: 3x3 patch (6 loads) + conv1 -> packed offsets ----
    h2 p01[3][3], p2p[3][3];
#pragma unroll
    for (int r = 0; r < 3; ++r) {
        const int base = (i + r + PADR) * PC + (j + PADC);
        const uint4 qa = reinterpret_cast<const uint4a8*>(xb2 + base)->v;
        const uint2 qb = xb2[base + 2];
        p01[r][0] = uint_as_h2(qa.x); p2p[r][0] = uint_as_h2(qa.y);
        p01[r][1] = uint_as_h2(qa.z); p2p[r][1] = uint_as_h2(qa.w);
        p01[r][2] = uint_as_h2(qb.x); p2p[r][2] = uint_as_h2(qb.y);
    }

    unsigned pk[KK];
#pragma unroll
    for (int k = 0; k < KK; ++k) {
        float dy = s_b[2 * k], dx = s_b[2 * k + 1];
        const uint4* wk = &s_w1h[k * 9];
#pragma unroll
        for (int r = 0; r < 3; ++r)
#pragma unroll
            for (int s = 0; s < 3; ++s) {
                const uint4 wq = wk[r * 3 + s];
                dy = fdot2f(uint_as_h2(wq.x), p01[r][s], dy);
                dy = fdot2f(uint_as_h2(wq.y), p2p[r][s], dy);
                dx = fdot2f(uint_as_h2(wq.z), p01[r][s], dx);
                dx = fdot2f(uint_as_h2(wq.w), p2p[r][s], dx);
            }
        pk[k] = h2_as_uint(pkrtz(dy, dx));
    }

    // ---- phase B: 2 corner-row dwordx4 loads/tap + pk bilinear + fdot2 ----
    const float fi = (float)(i + PADR);
    const float fj = (float)(j + PADC);
    float acc0 = s_b2[0], acc1 = s_b2[1], acc2 = s_b2[2];

#pragma unroll
    for (int k = 0; k < KK; ++k) {
        const uint4 wa = s_w2a[k];
        const uint2 wb = s_w2b[k];
        const h2 d = uint_as_h2(pk[k]);
        const float syp = fi + (float)(k / 3) + (float)d.x;  // always > 0
        const float sxp = fj + (float)(k % 3) + (float)d.y;  // always > 0
        const int y0 = (int)syp;  // trunc == floor
        const int x0 = (int)sxp;
        const float fy = syp - (float)y0;
        const float fx = sxp - (float)x0;

        const int a00 = y0 * PC + x0;
        // one 16B load per corner row: {c00 | c01} and {c10 | c11}
        const uint4 top = reinterpret_cast<const uint4a8*>(xb2 + a00)->v;
        const uint4 bot = reinterpret_cast<const uint4a8*>(xb2 + a00 + PC)->v;

        const float wy0 = 1.f - fy, wx0 = 1.f - fx;
        const float w00 = wy0 * wx0, w01 = wy0 * fx;
        const float w10 = fy * wx0, w11 = fy * fx;
        const h2 h00 = pkrtz(w00, w00);
        const h2 h01 = pkrtz(w01, w01);
        const h2 h10 = pkrtz(w10, w10);
        const h2 h11 = pkrtz(w11, w11);

        h2 vg = h00 * uint_as_h2(top.x);
        vg = h01 * uint_as_h2(top.z) + vg;
        vg = h10 * uint_as_h2(bot.x) + vg;
        vg = h11 * uint_as_h2(bot.z) + vg;
        h2 ve = h00 * uint_as_h2(top.y);
        ve = h01 * uint_as_h2(top.w) + ve;
        ve = h10 * uint_as_h2(bot.y) + ve;
        ve = h11 * uint_as_h2(bot.w) + ve;

        acc0 = fdot2f(uint_as_h2(wa.x), vg, fdot2f(uint_as_h2(wa.y), ve, acc0));
        acc1 = fdot2f(uint_as_h2(wa.z), vg, fdot2f(uint_as_h2(wa.w), ve, acc1));
        acc2 = fdot2f(uint_as_h2(wb.x), vg, fdot2f(uint_as_h2(wb.y), ve, acc2));
    }

    float* ob = out + (size_t)b * COUT * HOWO + (size_t)i * WO + j;
    ob[0 * HOWO] = acc0;
    ob[1 * HOWO] = acc1;
    ob[2 * HOWO] = acc2;
}

// ---------------- fallback: R0-style fully fused (no workspace) ----------
__global__ __launch_bounds__(256) void deform_fused_kernel(
    const float* __restrict__ x, const float* __restrict__ w1,
    const float* __restrict__ b1, const float* __restrict__ w2,
    const float* __restrict__ b2, float* __restrict__ out)
{
    __shared__ float s_w1[18 * 27];
    __shared__ float s_b1[18];
    __shared__ float s_w2[COUT * CIN * KK];
    __shared__ float s_b2[COUT];
    for (int t = threadIdx.x; t < 18 * 27; t += blockDim.x) s_w1[t] = w1[t];
    if (threadIdx.x < 18) s_b1[threadIdx.x] = b1[threadIdx.x];
    if (threadIdx.x < COUT * CIN * KK) s_w2[threadIdx.x] = w2[threadIdx.x];
    if (threadIdx.x < COUT) s_b2[threadIdx.x] = b2[threadIdx.x];
    __syncthreads();
    const int idx = blockIdx.x * blockDim.x + threadIdx.x;
    if (idx >= BB * HOWO) return;
    const int j = idx % WO;
    const int tmp = idx / WO;
    const int i = tmp % HO;
    const int b = tmp / HO;
    const float* xb = x + (size_t)b * CIN * HW;
    float patch[CIN][3][3];
#pragma unroll
    for (int c = 0; c < CIN; ++c)
#pragma unroll
        for (int r = 0; r < 3; ++r)
#pragma unroll
            for (int s = 0; s < 3; ++s)
                patch[c][r][s] = xb[c * HW + (i + r) * WW + (j + s)];
    float acc0 = s_b2[0], acc1 = s_b2[1], acc2 = s_b2[2];
#pragma unroll
    for (int k = 0; k < KK; ++k) {
        const int ky = k / 3, kx = k % 3;
        float dy = s_b1[2 * k], dx = s_b1[2 * k + 1];
        const float* wy = &s_w1[(2 * k) * 27];
        const float* wx = &s_w1[(2 * k + 1) * 27];
        int t = 0;
#pragma unroll
        for (int c = 0; c < CIN; ++c)
#pragma unroll
            for (int r = 0; r < 3; ++r)
#pragma unroll
                for (int s = 0; s < 3; ++s, ++t) {
                    const float pv = patch[c][r][s];
                    dy += pv * wy[t];
                    dx += pv * wx[t];
                }
        const float sy = (float)(i + ky) + dy;
        const float sx = (float)(j + kx) + dx;
        const float y0f = floorf(sy), x0f = floorf(sx);
        const float fy = sy - y0f, fx = sx - x0f;
        const int y0 = (int)y0f, x0 = (int)x0f;
        float v0 = 0.f, v1 = 0.f, v2 = 0.f;
#pragma unroll
        for (int cy = 0; cy < 2; ++cy) {
            const int iy = y0 + cy;
            const float wyf = cy ? fy : (1.f - fy);
            const bool vy = (iy >= 0) && (iy < HH);
            const int iyc = iy < 0 ? 0 : (iy > HH - 1 ? HH - 1 : iy);
#pragma unroll
            for (int cx = 0; cx < 2; ++cx) {
                const int ix = x0 + cx;
                const float wxf = cx ? fx : (1.f - fx);
                const bool vx = (ix >= 0) && (ix < WW);
                const int ixc = ix < 0 ? 0 : (ix > WW - 1 ? WW - 1 : ix);
                const float wgt = (vy && vx) ? (wyf * wxf) : 0.f;
                const int off = iyc * WW + ixc;
                v0 += wgt * xb[0 * HW + off];
                v1 += wgt * xb[1 * HW + off];
                v2 += wgt * xb[2 * HW + off];
            }
        }
#pragma unroll
        for (int o = 0; o < COUT; ++o) {
            const float c0 = s_w2[(o * CIN + 0) * KK + k];
            const float c1 = s_w2[(o * CIN + 1) * KK + k];
            const float c2 = s_w2[(o * CIN + 2) * KK + k];
            const float contrib = c0 * v0 + c1 * v1 + c2 * v2;
            if (o == 0) acc0 += contrib;
            else if (o == 1) acc1 += contrib;
            else acc2 += contrib;
        }
    }
    float* ob = out + (size_t)b * COUT * HOWO + (size_t)i * WO + j;
    ob[0 * HOWO] = acc0;
    ob[1 * HOWO] = acc1;
    ob[2 * HOWO] = acc2;
}

extern "C" void kernel_launch(void* const* d_in, const int* in_sizes, int n_in,
                              void* d_out, int out_size, void* d_ws, size_t ws_size,
                              hipStream_t stream) {
    const float* x  = (const float*)d_in[0];
    const float* w1 = (const float*)d_in[1];
    const float* b1 = (const float*)d_in[2];
    const float* w2 = (const float*)d_in[3];
    const float* b2 = (const float*)d_in[4];
    float* out = (float*)d_out;

    if (ws_size >= XP_BYTES) {
        uint2* xp = (uint2*)d_ws;
        {
            const int total = BB * PR * (PC / 2);
            repack_padh2<<<(total + 255) / 256, 256, 0, stream>>>(x, xp);
        }
        {
            const int total = BB * HOWO;
            deform_fused10<<<(total + 255) / 256, 256, 0, stream>>>(
                xp, w1, b1, w2, b2, out);
        }
    } else {
        const int total = BB * HOWO;
        deform_fused_kernel<<<(total + 255) / 256, 256, 0, stream>>>(
            x, w1, b1, w2, b2, out);
    }
}